// Round 1
// baseline (248.640 us; speedup 1.0000x reference)
//
#include <hip/hip_runtime.h>

// EdgeModel: out = relu(cat[src(64),dest(64),edge(32)] @ w1[160,128] + b1) @ w2[128,32] + b2
// E = 1,600,000 rows, f32 in/out, bf16 MFMA compute (threshold 8.8e-2 >> ~1e-2 bf16 err).
//
// Structure: persistent 512 blocks (2/CU), 256 thr = 4 waves, 128 rows/tile, 32 rows/wave.
// w1 staged once/block into LDS in MFMA-fragment order (conflict-free ds_read_b128);
// w2 + biases in registers. A-operand loaded global->reg (8 contiguous floats/lane).
// GEMM2 via wave-private XOR-swizzled LDS h round-trip (no block barriers in main loop).

typedef float  f32x4  __attribute__((ext_vector_type(4)));
typedef short  s16x8  __attribute__((ext_vector_type(8)));

__device__ __forceinline__ unsigned short f2bf(float f) {
    // RTNE float -> bf16 bits
    unsigned int u = __float_as_uint(f);
    u += 0x7FFFu + ((u >> 16) & 1u);
    return (unsigned short)(u >> 16);
}

__global__ __launch_bounds__(256, 2) void edge_mlp(
    const float* __restrict__ src, const float* __restrict__ dst,
    const float* __restrict__ edg, const float* __restrict__ w1,
    const float* __restrict__ b1, const float* __restrict__ w2,
    const float* __restrict__ b2, float* __restrict__ out, int ntiles)
{
    // LDS: w1 fragments 40*64*16B = 40KB ; h buffers 4 waves * 16x128 bf16 = 16KB
    __shared__ __align__(16) unsigned short w1s[40 * 64 * 8];
    __shared__ __align__(16) unsigned short hbuf[4][16 * 128];

    const int t    = threadIdx.x;
    const int lane = t & 63;
    const int wid  = t >> 6;
    const int rq   = lane >> 4;   // 0..3
    const int rr   = lane & 15;   // 0..15

    // ---- stage w1 into fragment-order LDS (once per block) ----
    // frag f = kk*8+n ; lane l element j = w1[kk*32 + (l>>4)*8 + j][n*16 + (l&15)]
    for (int s = t; s < 40 * 64; s += 256) {
        const int f  = s >> 6, l = s & 63;
        const int kk = f >> 3, n = f & 7;
        const int k0 = kk * 32 + ((l >> 4) << 3);
        const int cl = (n << 4) + (l & 15);
        union { s16x8 v; unsigned short s16[8]; } r;
#pragma unroll
        for (int j = 0; j < 8; ++j)
            r.s16[j] = f2bf(w1[(k0 + j) * 128 + cl]);
        *reinterpret_cast<s16x8*>(&w1s[s * 8]) = r.v;
    }

    // ---- w2 fragments + biases into registers ----
    s16x8 w2f[4][2];
#pragma unroll
    for (int kk2 = 0; kk2 < 4; ++kk2)
#pragma unroll
        for (int n2 = 0; n2 < 2; ++n2) {
            union { s16x8 v; unsigned short s16[8]; } r;
#pragma unroll
            for (int j = 0; j < 8; ++j)
                r.s16[j] = f2bf(w2[(kk2 * 32 + (rq << 3) + j) * 32 + n2 * 16 + rr]);
            w2f[kk2][n2] = r.v;
        }
    float b1c[8], b2c[2];
#pragma unroll
    for (int n = 0; n < 8; ++n) b1c[n] = b1[n * 16 + rr];
#pragma unroll
    for (int n2 = 0; n2 < 2; ++n2) b2c[n2] = b2[n2 * 16 + rr];

    __syncthreads();

    unsigned short* hw = &hbuf[wid][0];

    for (int tile = blockIdx.x; tile < ntiles; tile += gridDim.x) {
        const size_t base = (size_t)tile * 128 + (size_t)wid * 32;

        // ---- GEMM1: acc[rf][n] = x[32 rows] @ w1, bias-initialized ----
        f32x4 acc[2][8];
#pragma unroll
        for (int rf = 0; rf < 2; ++rf)
#pragma unroll
            for (int n = 0; n < 8; ++n)
                acc[rf][n] = (f32x4){b1c[n], b1c[n], b1c[n], b1c[n]};

#pragma unroll
        for (int kk = 0; kk < 5; ++kk) {
            const float* sp; int cols, cofs;
            if      (kk == 0) { sp = src; cols = 64; cofs = 0;  }
            else if (kk == 1) { sp = src; cols = 64; cofs = 32; }
            else if (kk == 2) { sp = dst; cols = 64; cofs = 0;  }
            else if (kk == 3) { sp = dst; cols = 64; cofs = 32; }
            else              { sp = edg; cols = 32; cofs = 0;  }

            s16x8 a[2];
#pragma unroll
            for (int rf = 0; rf < 2; ++rf) {
                const float* p = sp + (base + rf * 16 + rr) * cols + cofs + (rq << 3);
                f32x4 v0 = *reinterpret_cast<const f32x4*>(p);
                f32x4 v1 = *reinterpret_cast<const f32x4*>(p + 4);
                union { s16x8 v; unsigned short s16[8]; } r;
                r.s16[0] = f2bf(v0.x); r.s16[1] = f2bf(v0.y);
                r.s16[2] = f2bf(v0.z); r.s16[3] = f2bf(v0.w);
                r.s16[4] = f2bf(v1.x); r.s16[5] = f2bf(v1.y);
                r.s16[6] = f2bf(v1.z); r.s16[7] = f2bf(v1.w);
                a[rf] = r.v;
            }
#pragma unroll
            for (int n = 0; n < 8; ++n) {
                s16x8 b = *reinterpret_cast<const s16x8*>(&w1s[((kk * 8 + n) * 64 + lane) * 8]);
                acc[0][n] = __builtin_amdgcn_mfma_f32_16x16x32_bf16(a[0], b, acc[0][n], 0, 0, 0);
                acc[1][n] = __builtin_amdgcn_mfma_f32_16x16x32_bf16(a[1], b, acc[1][n], 0, 0, 0);
            }
        }

        // ---- GEMM2 per 16-row fragment: h -> wave-private LDS -> MFMA -> store ----
#pragma unroll
        for (int rf = 0; rf < 2; ++rf) {
            // write relu(h) as bf16, XOR-swizzled rows (kills 256B-stride bank conflict)
#pragma unroll
            for (int n = 0; n < 8; ++n)
#pragma unroll
                for (int j = 0; j < 4; ++j) {
                    const int row  = rq * 4 + j;              // 0..15
                    const int addr = ((row * 256 + (n * 16 + rr) * 2) ^ ((row & 7) << 4));
                    float v = acc[rf][n][j];
                    v = v > 0.0f ? v : 0.0f;
                    *reinterpret_cast<unsigned short*>(
                        reinterpret_cast<char*>(hw) + addr) = f2bf(v);
                }
            asm volatile("" ::: "memory");  // keep DS program order (in-order per wave in HW)

            f32x4 acc2[2];
#pragma unroll
            for (int n2 = 0; n2 < 2; ++n2)
                acc2[n2] = (f32x4){b2c[n2], b2c[n2], b2c[n2], b2c[n2]};

#pragma unroll
            for (int kk2 = 0; kk2 < 4; ++kk2) {
                const int row  = rr;
                const int addr = ((row * 256 + kk2 * 64 + rq * 16) ^ ((row & 7) << 4));
                s16x8 a2 = *reinterpret_cast<const s16x8*>(
                    reinterpret_cast<const char*>(hw) + addr);
                acc2[0] = __builtin_amdgcn_mfma_f32_16x16x32_bf16(a2, w2f[kk2][0], acc2[0], 0, 0, 0);
                acc2[1] = __builtin_amdgcn_mfma_f32_16x16x32_bf16(a2, w2f[kk2][1], acc2[1], 0, 0, 0);
            }
            asm volatile("" ::: "memory");  // reads of this rf before next rf's writes

            // store: D row = rq*4+j, col = n2*16+rr  (coalesced 64B per 16-lane group)
#pragma unroll
            for (int n2 = 0; n2 < 2; ++n2)
#pragma unroll
                for (int j = 0; j < 4; ++j) {
                    const size_t row = base + rf * 16 + rq * 4 + j;
                    out[row * 32 + n2 * 16 + rr] = acc2[n2][j];
                }
        }
    }
}

// Scalar tail for E % 128 != 0 (not hit for E = 1,600,000; kept for safety)
__global__ void edge_mlp_tail(
    const float* __restrict__ src, const float* __restrict__ dst,
    const float* __restrict__ edg, const float* __restrict__ w1,
    const float* __restrict__ b1, const float* __restrict__ w2,
    const float* __restrict__ b2, float* __restrict__ out,
    long long row0, long long E)
{
    const long long r = row0 + blockIdx.x;
    if (r >= E) return;
    __shared__ float h[128];
    const int t = threadIdx.x;  // 128 threads
    float acc = b1[t];
    for (int k = 0; k < 64; ++k) acc += src[r * 64 + k] * w1[k * 128 + t];
    for (int k = 0; k < 64; ++k) acc += dst[r * 64 + k] * w1[(64 + k) * 128 + t];
    for (int k = 0; k < 32; ++k) acc += edg[r * 32 + k] * w1[(128 + k) * 128 + t];
    h[t] = acc > 0.0f ? acc : 0.0f;
    __syncthreads();
    if (t < 32) {
        float o = b2[t];
        for (int k = 0; k < 128; ++k) o += h[k] * w2[k * 32 + t];
        out[r * 32 + t] = o;
    }
}

extern "C" void kernel_launch(void* const* d_in, const int* in_sizes, int n_in,
                              void* d_out, int out_size, void* d_ws, size_t ws_size,
                              hipStream_t stream)
{
    const float* src = (const float*)d_in[0];
    const float* dst = (const float*)d_in[1];
    const float* edg = (const float*)d_in[2];
    // d_in[3] = u (unused), d_in[4] = batch (unused)
    const float* w1  = (const float*)d_in[5];
    const float* b1  = (const float*)d_in[6];
    const float* w2  = (const float*)d_in[7];
    const float* b2  = (const float*)d_in[8];
    float* out = (float*)d_out;

    const long long E      = (long long)in_sizes[0] / 64;
    const int       ntiles = (int)(E / 128);
    const long long rem    = E - (long long)ntiles * 128;

    if (ntiles > 0) {
        int grid = ntiles < 512 ? ntiles : 512;
        edge_mlp<<<dim3(grid), dim3(256), 0, stream>>>(
            src, dst, edg, w1, b1, w2, b2, out, ntiles);
    }
    if (rem > 0) {
        edge_mlp_tail<<<dim3((unsigned)rem), dim3(128), 0, stream>>>(
            src, dst, edg, w1, b1, w2, b2, out, (long long)ntiles * 128, E);
    }
}